// Round 2
// baseline (264.681 us; speedup 1.0000x reference)
//
#include <hip/hip_runtime.h>
#include <stdint.h>

#define Bn 4
#define Sn 2048
#define En 1024
#define Hn 16
#define Dn 64

// 0.125 * log2(e) folded into Q at projection time (softmax runs in exp2 domain)
#define QSC 0.18033688011112f

typedef unsigned short u16;
typedef short s16x8 __attribute__((ext_vector_type(8)));
typedef float f32x4 __attribute__((ext_vector_type(4)));
typedef float f32x16 __attribute__((ext_vector_type(16)));

#define MFMA16x16x32 __builtin_amdgcn_mfma_f32_16x16x32_bf16
#define MFMA32x32x16 __builtin_amdgcn_mfma_f32_32x32x16_bf16

__device__ __forceinline__ u16 f2bf(float f) {
  union { float f; uint32_t u; } v; v.f = f;
  uint32_t u = v.u;
  u += 0x7fffu + ((u >> 16) & 1u);   // round-to-nearest-even
  return (u16)(u >> 16);
}
__device__ __forceinline__ uint32_t f2u(float f) {
  union { float f; uint32_t u; } v; v.f = f; return v.u;
}

#define AS1 __attribute__((address_space(1)))
#define AS3 __attribute__((address_space(3)))
__device__ __forceinline__ void gload_lds16(const void* g, void* l) {
  __builtin_amdgcn_global_load_lds((const AS1 uint32_t*)g, (AS3 uint32_t*)l, 16, 0, 0);
}

// ---------------- fused prep: cast x + repack Wqkv + repack Wo + pack bias ----
__global__ __launch_bounds__(256) void prep_all(
    const float4* __restrict__ x4, ushort4* __restrict__ xb4,
    const float* __restrict__ Wq, const float* __restrict__ Wk,
    const float* __restrict__ Wv, u16* __restrict__ WallT,
    const float* __restrict__ Wo, u16* __restrict__ WoT,
    const float* __restrict__ bq, const float* __restrict__ bk,
    const float* __restrict__ bv, float* __restrict__ biasA)
{
  __shared__ float t[64][65];
  const int tid = threadIdx.x;
  int blk = blockIdx.x;

  if (blk < 8192) {                     // cast x
    int i = blk * 256 + tid;
    float4 v = x4[i];
    ushort4 o;
    o.x = f2bf(v.x); o.y = f2bf(v.y); o.z = f2bf(v.z); o.w = f2bf(v.w);
    xb4[i] = o;
    return;
  }
  blk -= 8192;
  if (blk < 768) {                      // repack Wq/Wk/Wv
    const int e0 = (blk & 15) * 64;
    const int sh = blk >> 4;            // sec*16 + h
    const int sec = sh >> 4, h = sh & 15;
    const float* W = (sec == 0) ? Wq : (sec == 1) ? Wk : Wv;
    const float* Wh = W + (size_t)h * En * Dn;
    const int d = tid & 63, er = tid >> 6;
#pragma unroll
    for (int ee = 0; ee < 64; ee += 4)
      t[ee + er][d] = Wh[(size_t)(e0 + ee + er) * Dn + d];
    __syncthreads();
    const int dd = tid >> 2, eo = (tid & 3) * 16;
    u16* dst = WallT + (size_t)(sec * 1024 + h * 64 + dd) * En + e0 + eo;
#pragma unroll
    for (int i = 0; i < 16; i += 4) {
      ushort4 o;
      o.x = f2bf(t[eo + i + 0][dd]);
      o.y = f2bf(t[eo + i + 1][dd]);
      o.z = f2bf(t[eo + i + 2][dd]);
      o.w = f2bf(t[eo + i + 3][dd]);
      *(ushort4*)(dst + i) = o;
    }
    return;
  }
  blk -= 768;
  if (blk < 256) {                      // repack Wo
    const int k0 = (blk & 15) * 64;
    const int n0 = (blk >> 4) * 64;
    const int c = tid & 63, r4 = tid >> 6;
#pragma unroll
    for (int rr = 0; rr < 64; rr += 4)
      t[rr + r4][c] = Wo[(size_t)(k0 + rr + r4) * En + n0 + c];
    __syncthreads();
    const int n = tid >> 2, ko = (tid & 3) * 16;
    u16* dst = WoT + (size_t)(n0 + n) * (Hn * Dn) + k0 + ko;
#pragma unroll
    for (int i = 0; i < 16; i += 4) {
      ushort4 o;
      o.x = f2bf(t[ko + i + 0][n]);
      o.y = f2bf(t[ko + i + 1][n]);
      o.z = f2bf(t[ko + i + 2][n]);
      o.w = f2bf(t[ko + i + 3][n]);
      *(ushort4*)(dst + i) = o;
    }
    return;
  }
  blk -= 256;
  int n = blk * 256 + tid;              // bias pack
  if (n < 3 * Hn * Dn) {
    int sec = n >> 10, rr = n & 1023;
    const float* bs = (sec == 0) ? bq : (sec == 1) ? bk : bv;
    biasA[n] = bs[rr];
  }
}

// ---------------- GEMM via 32x32x16 MFMA: C[M,N] = A[M,K] * Bt[N,K]^T + bias --
// 128x128 tile, BK=64, 256 threads / 4 waves (2M x 2N, wave-tile 64x64 = 2x2
// 32x32 MFMA tiles). 32x32x16 halves LDS-read traffic per FLOP vs 16x16x32
// (1 b128 A-read feeds 32768 FLOP) and raises the MFMA ceiling (m119: 2495 TF).
// LDS = 64 KiB (2 dbuf x (A 16K + B 16K)) -> 2 blocks/CU: cross-block overlap
// hides the per-K-tile vmcnt gate (m114). Grid = exact multiple of 512
// (2 blocks x 256 CUs) -> no empty-CU tail rounds.
// XOR-swizzled LDS rows (seg ^= row&7, 128B rows) with pre-swizzled global
// source (both-sides involution, rule 21); 32-lane column b128 reads land
// 8 lanes/seg-group = data-volume minimum -> conflict-free.
// XCD swizzle: mi-major per XCD (each XCD owns 8 contiguous m-panels; B
// panels stream through L2/L3).
// Fragment maps (verified conventions, m74/m101):
//   A: row=lane&31, k=(lane>>5)*8+e  |  B: col=lane&31, same k
//   C/D: col=lane&31, row=(rg&3)+8*(rg>>2)+4*(lane>>5)
// MODE 0: QKV epilogue (Q pre-scaled QSC, K direct, V^T via LDS transpose)
// MODE 1: fp32 row-major output, N=1024
template<int MODE>
__global__ __launch_bounds__(256, 2) void gemm32(
    const u16* __restrict__ A, const u16* __restrict__ Bt,
    const float* __restrict__ bias, int nTn,
    u16* __restrict__ q_out, u16* __restrict__ k_out, u16* __restrict__ v_out,
    float* __restrict__ f_out)
{
  extern __shared__ __align__(16) u16 smem[];   // [A0|A1|B0|B1] x 8192 u16

  const int tid  = threadIdx.x;
  const int L    = blockIdx.x;
  const int tpx  = gridDim.x >> 3;            // tiles per XCD
  const int rl   = L >> 3;
  const int mi   = (L & 7) * (tpx / nTn) + rl / nTn;
  const int ni   = rl % nTn;
  const int m0   = mi * 128;
  const int n0   = ni * 128;

  const int w    = tid >> 6;
  const int lane = tid & 63;
  const int wm   = w >> 1, wn = w & 1;
  const int l31  = lane & 31;
  const int half = lane >> 5;
  const int l7   = lane & 7;

  // staging: thread owns 16B chunk; pre-swizzled global segment
  const int sr = tid >> 3, sl = tid & 7;
  const int sg = sl ^ (sr & 7);
  const u16* gA = A  + (size_t)(m0 + sr) * En + sg * 8;
  const u16* gB = Bt + (size_t)(n0 + sr) * En + sg * 8;
  const int lb = tid * 8;

  f32x16 acc[2][2];
#pragma unroll
  for (int x = 0; x < 2; ++x)
#pragma unroll
    for (int y = 0; y < 2; ++y)
#pragma unroll
      for (int rg = 0; rg < 16; ++rg) acc[x][y][rg] = 0.f;

  auto stage = [&](int t) {
    const int db = t & 1;
    const int k0 = t * 64;
    u16* dA = smem + db * 8192 + lb;
    u16* dB = smem + 16384 + db * 8192 + lb;
#pragma unroll
    for (int c = 0; c < 4; ++c) {               // 4 chunks of 32 rows each
      gload_lds16(gA + (size_t)(c * 32) * En + k0, dA + c * 2048);
      gload_lds16(gB + (size_t)(c * 32) * En + k0, dB + c * 2048);
    }
  };

  stage(0);
  asm volatile("s_waitcnt vmcnt(0)" ::: "memory");
  __builtin_amdgcn_s_barrier();

  for (int t = 0; t < 16; ++t) {
    if (t < 15) stage(t + 1);                   // fills other buffer
    const u16* cA = smem + (t & 1) * 8192;
    const u16* cB = smem + 16384 + (t & 1) * 8192;

    s16x8 av[2][4], bv[2][4];
#pragma unroll
    for (int x = 0; x < 2; ++x) {
      const u16* pa = cA + (size_t)(wm * 64 + x * 32 + l31) * 64;
      const u16* pb = cB + (size_t)(wn * 64 + x * 32 + l31) * 64;
#pragma unroll
      for (int ks = 0; ks < 4; ++ks) {
        av[x][ks] = *(const s16x8*)&pa[((2 * ks + half) ^ l7) * 8];
        bv[x][ks] = *(const s16x8*)&pb[((2 * ks + half) ^ l7) * 8];
      }
    }
#pragma unroll
    for (int ks = 0; ks < 4; ++ks)
#pragma unroll
      for (int x = 0; x < 2; ++x)
#pragma unroll
        for (int y = 0; y < 2; ++y)
          acc[x][y] = MFMA32x32x16(av[x][ks], bv[y][ks], acc[x][y], 0, 0, 0);

    asm volatile("s_waitcnt vmcnt(0)" ::: "memory");   // next tile staged
    __builtin_amdgcn_s_barrier();
  }

  if (MODE == 0) {
    const int sec = n0 >> 10;                   // 0:Q 1:K 2:V (block-uniform)
    if (sec < 2) {
      const float osc = (sec == 0) ? QSC : 1.0f;
      u16* dst = (sec == 0) ? q_out : k_out;
      const int b = m0 >> 11;
#pragma unroll
      for (int y = 0; y < 2; ++y) {
        int col = n0 + wn * 64 + y * 32 + l31;
        float bvv = bias[col];
        int rr = col & 1023, h = rr >> 6, d = rr & 63;
#pragma unroll
        for (int x = 0; x < 2; ++x) {
          int rbase = (m0 & 2047) + wm * 64 + x * 32 + 4 * half;
#pragma unroll
          for (int rg = 0; rg < 16; ++rg) {
            int s = rbase + (rg & 3) + 8 * (rg >> 2);
            dst[(((size_t)b * Hn + h) * Sn + s) * Dn + d] =
                f2bf((acc[x][y][rg] + bvv) * osc);
          }
        }
      }
    } else {
      // V: transpose 128x128 C-tile through LDS, coalesced V^T stores
      u16* lC = smem;                           // [col][136] (34816 B)
#pragma unroll
      for (int y = 0; y < 2; ++y) {
        int cl = wn * 64 + y * 32 + l31;
        float bvv = bias[n0 + cl];
#pragma unroll
        for (int x = 0; x < 2; ++x) {
          int rbase = wm * 64 + x * 32 + 4 * half;
#pragma unroll
          for (int rg = 0; rg < 16; ++rg)
            lC[cl * 136 + rbase + (rg & 3) + 8 * (rg >> 2)] =
                f2bf(acc[x][y][rg] + bvv);
        }
      }
      __syncthreads();
      int c = tid >> 1, hh = tid & 1;
      int colg = (n0 & 1023) + c;
      int h = colg >> 6, d = colg & 63;
      int b = m0 >> 11;
      int s0 = (m0 & 2047) + hh * 64;
      const uint4* src = (const uint4*)&lC[c * 136 + hh * 64];
      uint4* dstv = (uint4*)&v_out[(((size_t)b * Hn + h) * Dn + d) * Sn + s0];
#pragma unroll
      for (int i = 0; i < 8; ++i) dstv[i] = src[i];
    }
  } else {
#pragma unroll
    for (int y = 0; y < 2; ++y) {
      int col = n0 + wn * 64 + y * 32 + l31;
      float bvv = bias[col];
#pragma unroll
      for (int x = 0; x < 2; ++x) {
        int rbase = m0 + wm * 64 + x * 32 + 4 * half;
#pragma unroll
        for (int rg = 0; rg < 16; ++rg) {
          int row = rbase + (rg & 3) + 8 * (rg >> 2);
          f_out[(size_t)row * 1024 + col] = acc[x][y][rg] + bvv;
        }
      }
    }
  }
}

// ---------------- flash attention v8 ----------------
__global__ __launch_bounds__(256, 4) void flash_attn(
    const u16* __restrict__ Qb, const u16* __restrict__ Kb,
    const u16* __restrict__ Vt, u16* __restrict__ conc)
{
  __shared__ __align__(16) u16 lK[2][64 * 64];   // [buf][kk][d] swizzled
  __shared__ __align__(16) u16 lV[2][64 * 64];   // [buf][d][kk] swizzled
  __shared__ __align__(16) u16 lP[4][16 * 64];   // [wave][q][kk], 16B XOR swizzle

  const int L   = blockIdx.x;
  const int bh  = L & 63;
  const int qt  = ((L >> 6) + (bh >> 2)) & 15;
  const int b   = bh >> 4, h = bh & 15;
  const int tid = threadIdx.x;
  const int w   = tid >> 6;
  const int lane = tid & 63;
  const int quad = lane >> 4;
  const int l15  = lane & 15;
  const int q0   = qt * 128;

  const u16* Qh = Qb + (size_t)bh * Sn * Dn;
  const u16* Kh = Kb + (size_t)bh * Sn * Dn;
  const u16* Vh = Vt + (size_t)bh * Dn * Sn;

  const int Q0m[2] = { q0 + w * 16, q0 + 64 + w * 16 };

  s16x8 aq[2][2];                      // Q fragments (B operand), pre-scaled
#pragma unroll
  for (int m = 0; m < 2; ++m)
#pragma unroll
    for (int c = 0; c < 2; ++c)
      aq[m][c] = *(const s16x8*)&Qh[(size_t)(Q0m[m] + l15) * Dn + c * 32 + quad * 8];

  s16x8 kones;                         // bf16 1.0 x8 (A-operand of l-sum MFMA)
#pragma unroll
  for (int i = 0; i < 8; ++i) kones[i] = (short)0x3F80;

  f32x4 acc[2][4];                     // O^T tiles: row d = dt*16+quad*4+r, col q = l15
#pragma unroll
  for (int m = 0; m < 2; ++m)
#pragma unroll
    for (int i = 0; i < 4; ++i) acc[m][i] = (f32x4){0.f, 0.f, 0.f, 0.f};
  const float NEG_INF = -__builtin_inff();
  float lrow[2] = {0.f, 0.f};

  const int sw0 = (quad ^ (l15 & 7)) * 8;
  const int sw1 = ((quad + 4) ^ (l15 & 7)) * 8;
  const int l7  = l15 & 7;

  const int ntiles = 2 * qt + 2;

  auto stage = [&](int kt) {
    int bufb = kt & 1;
    int kk0 = kt * 64;
#pragma unroll
    for (int c = 0; c < 2; ++c) {
      int idx = c * 256 + tid;         // 0..511
      int row = idx >> 3, sl = idx & 7;
      int sg = sl ^ (row & 7);
      gload_lds16(Kh + (size_t)(kk0 + row) * Dn + sg * 8, &lK[bufb][idx * 8]);
      gload_lds16(Vh + (size_t)row * Sn + kk0 + sg * 8, &lV[bufb][idx * 8]);
    }
  };

  stage(0);
  for (int kt = 0; kt < ntiles; ++kt) {
    const int kk0 = kt * 64;
    __syncthreads();                   // drains stage(kt); issued one compute ago
    if (kt + 1 < ntiles) stage(kt + 1);
    const u16* cK = lK[kt & 1];
    const u16* cV = lV[kt & 1];

#pragma unroll
    for (int m = 0; m < 2; ++m) {
      const int Q0 = Q0m[m];
      if (kk0 >= Q0 + 16) continue;    // sub-tile fully masked (wave-uniform)

      // S^T (pre-scaled, exp2 domain): lane = q-row l15, k = kk0 + ct*16 + quad*4 + r
      f32x4 sc[4];
#pragma unroll
      for (int ct = 0; ct < 4; ++ct) {
        s16x8 bk0 = *(const s16x8*)&cK[(ct * 16 + l15) * 64 + sw0];
        s16x8 bk1 = *(const s16x8*)&cK[(ct * 16 + l15) * 64 + sw1];
        f32x4 z = (f32x4){0.f, 0.f, 0.f, 0.f};
        z = MFMA16x16x32(bk0, aq[m][0], z, 0, 0, 0);
        z = MFMA16x16x32(bk1, aq[m][1], z, 0, 0, 0);
        sc[ct] = z;
      }

      const int qg = Q0 + l15;
      if (kk0 + 63 > Q0) {             // diagonal region: causal mask
#pragma unroll
        for (int ct = 0; ct < 4; ++ct)
#pragma unroll
          for (int r = 0; r < 4; ++r) {
            int kkg = kk0 + ct * 16 + quad * 4 + r;
            sc[ct][r] = (kkg <= qg) ? sc[ct][r] : NEG_INF;
          }
      }

      // P = exp2(sc) directly (shift-invariant softmax; masked -inf -> 0)
#pragma unroll
      for (int ct = 0; ct < 4; ++ct)
#pragma unroll
        for (int r = 0; r < 4; ++r)
          sc[ct][r] = __builtin_amdgcn_exp2f(sc[ct][r]);

      // P^T -> lP (truncation pack via v_perm; 16B XOR swizzle, bank-uniform)
      u16* Pw = &lP[w][0];
#pragma unroll
      for (int ct = 0; ct < 4; ++ct) {
        uint32_t d0 = __builtin_amdgcn_perm(f2u(sc[ct][1]), f2u(sc[ct][0]), 0x07060302);
        uint32_t d1 = __builtin_amdgcn_perm(f2u(sc[ct][3]), f2u(sc[ct][2]), 0x07060302);
        uint2 pk; pk.x = d0; pk.y = d1;
        int seg = (ct * 2 + (quad >> 1)) ^ l7;
        *(uint2*)&Pw[l15 * 64 + seg * 8 + (quad & 1) * 4] = pk;
      }
      __builtin_amdgcn_s_waitcnt(0xc07f);   // lgkmcnt(0)

      s16x8 ap0 = *(const s16x8*)&Pw[l15 * 64 + (quad ^ l7) * 8];
      s16x8 ap1 = *(const s16x8*)&Pw[l15 * 64 + ((quad + 4) ^ l7) * 8];

      // l-sum of (truncated) P via ones-row MFMA: C[i][q] = sum_k P[k][q]
      f32x4 zl = (f32x4){0.f, 0.f, 0.f, 0.f};
      zl = MFMA16x16x32(kones, ap0, zl, 0, 0, 0);
      zl = MFMA16x16x32(kones, ap1, zl, 0, 0, 0);

#pragma unroll
      for (int dt = 0; dt < 4; ++dt) {
        s16x8 bv0 = *(const s16x8*)&cV[(dt * 16 + l15) * 64 + sw0];
        s16x8 bv1 = *(const s16x8*)&cV[(dt * 16 + l15) * 64 + sw1];
        acc[m][dt] = MFMA16x16x32(bv0, ap0, acc[m][dt], 0, 0, 0);
        acc[m][dt] = MFMA16x16x32(bv1, ap1, acc[m][dt], 0, 0, 0);
      }
      lrow[m] += zl[0];
    }
  }

  // epilogue: O = acc^T / l -> conc [B, S, H*D] bf16 (lane l15 = q-row)
#pragma unroll
  for (int m = 0; m < 2; ++m) {
    float inv = 1.0f / lrow[m];
    int qg = Q0m[m] + l15;
#pragma unroll
    for (int dt = 0; dt < 4; ++dt) {
      ushort4 o;
      o.x = f2bf(acc[m][dt][0] * inv);
      o.y = f2bf(acc[m][dt][1] * inv);
      o.z = f2bf(acc[m][dt][2] * inv);
      o.w = f2bf(acc[m][dt][3] * inv);
      *(ushort4*)&conc[((size_t)b * Sn + qg) * (Hn * Dn) + h * Dn + dt * 16 + quad * 4] = o;
    }
  }
}

// ---------------- launch ----------------
extern "C" void kernel_launch(void* const* d_in, const int* in_sizes, int n_in,
                              void* d_out, int out_size, void* d_ws, size_t ws_size,
                              hipStream_t stream)
{
  const float* x  = (const float*)d_in[0];
  const float* Wq = (const float*)d_in[1];
  const float* Wk = (const float*)d_in[2];
  const float* Wv = (const float*)d_in[3];
  const float* bq = (const float*)d_in[4];
  const float* bk = (const float*)d_in[5];
  const float* bv = (const float*)d_in[6];
  const float* Wo = (const float*)d_in[7];
  const float* bo = (const float*)d_in[8];
  float* out = (float*)d_out;

  char* p = (char*)d_ws;
  u16* xb    = (u16*)p; p += (size_t)Bn * Sn * En * sizeof(u16);
  u16* WallT = (u16*)p; p += (size_t)3 * Hn * Dn * En * sizeof(u16);
  u16* WoT   = (u16*)p; p += (size_t)En * Hn * Dn * sizeof(u16);
  float* biasA = (float*)p; p += (size_t)3 * Hn * Dn * sizeof(float);
  u16* Qb    = (u16*)p; p += (size_t)Bn * Hn * Sn * Dn * sizeof(u16);
  u16* Kb    = (u16*)p; p += (size_t)Bn * Hn * Sn * Dn * sizeof(u16);
  u16* Vt    = (u16*)p; p += (size_t)Bn * Hn * Dn * Sn * sizeof(u16);
  u16* conc  = (u16*)p; p += (size_t)Bn * Sn * Hn * Dn * sizeof(u16);

  // fused prep: 8192 cast + 768 qkv-repack + 256 wo-repack + 12 bias
  prep_all<<<9228, 256, 0, stream>>>((const float4*)x, (ushort4*)xb,
                                     Wq, Wk, Wv, WallT, Wo, WoT,
                                     bq, bk, bv, biasA);

  size_t smem32 = 4 * 8192 * sizeof(u16);   // 64 KiB -> 2 blocks/CU

  // QKV: [8192,1024] x [1024,3072]; grid 1536 = 3 exact co-residency rounds
  gemm32<0><<<1536, 256, smem32, stream>>>(xb, WallT, biasA, 24,
                                           Qb, Kb, Vt, nullptr);

  flash_attn<<<(Sn / 128) * Bn * Hn, 256, 0, stream>>>(Qb, Kb, Vt, conc);

  // out: [8192,1024] x [1024,1024] + bo -> fp32; grid 512 = 1 exact round
  gemm32<1><<<512, 256, smem32, stream>>>(conc, WoT, bo, 8,
                                          nullptr, nullptr, nullptr, out);
}

// Round 3
// 254.943 us; speedup vs baseline: 1.0382x; 1.0382x over previous
//
#include <hip/hip_runtime.h>
#include <stdint.h>

#define Bn 4
#define Sn 2048
#define En 1024
#define Hn 16
#define Dn 64

// 0.125 * log2(e) folded into Q at projection time (softmax runs in exp2 domain)
#define QSC 0.18033688011112f

typedef unsigned short u16;
typedef short s16x8 __attribute__((ext_vector_type(8)));
typedef float f32x4 __attribute__((ext_vector_type(4)));

#define MFMA16x16x32 __builtin_amdgcn_mfma_f32_16x16x32_bf16

__device__ __forceinline__ u16 f2bf(float f) {
  union { float f; uint32_t u; } v; v.f = f;
  uint32_t u = v.u;
  u += 0x7fffu + ((u >> 16) & 1u);   // round-to-nearest-even
  return (u16)(u >> 16);
}
__device__ __forceinline__ uint32_t f2u(float f) {
  union { float f; uint32_t u; } v; v.f = f; return v.u;
}

#define AS1 __attribute__((address_space(1)))
#define AS3 __attribute__((address_space(3)))
__device__ __forceinline__ void gload_lds16(const void* g, void* l) {
  __builtin_amdgcn_global_load_lds((const AS1 uint32_t*)g, (AS3 uint32_t*)l, 16, 0, 0);
}

// ---------------- fused prep: cast x + repack Wqkv + repack Wo + pack bias ----
__global__ __launch_bounds__(256) void prep_all(
    const float4* __restrict__ x4, ushort4* __restrict__ xb4,
    const float* __restrict__ Wq, const float* __restrict__ Wk,
    const float* __restrict__ Wv, u16* __restrict__ WallT,
    const float* __restrict__ Wo, u16* __restrict__ WoT,
    const float* __restrict__ bq, const float* __restrict__ bk,
    const float* __restrict__ bv, float* __restrict__ biasA)
{
  __shared__ float t[64][65];
  const int tid = threadIdx.x;
  int blk = blockIdx.x;

  if (blk < 8192) {                     // cast x
    int i = blk * 256 + tid;
    float4 v = x4[i];
    ushort4 o;
    o.x = f2bf(v.x); o.y = f2bf(v.y); o.z = f2bf(v.z); o.w = f2bf(v.w);
    xb4[i] = o;
    return;
  }
  blk -= 8192;
  if (blk < 768) {                      // repack Wq/Wk/Wv
    const int e0 = (blk & 15) * 64;
    const int sh = blk >> 4;            // sec*16 + h
    const int sec = sh >> 4, h = sh & 15;
    const float* W = (sec == 0) ? Wq : (sec == 1) ? Wk : Wv;
    const float* Wh = W + (size_t)h * En * Dn;
    const int d = tid & 63, er = tid >> 6;
#pragma unroll
    for (int ee = 0; ee < 64; ee += 4)
      t[ee + er][d] = Wh[(size_t)(e0 + ee + er) * Dn + d];
    __syncthreads();
    const int dd = tid >> 2, eo = (tid & 3) * 16;
    u16* dst = WallT + (size_t)(sec * 1024 + h * 64 + dd) * En + e0 + eo;
#pragma unroll
    for (int i = 0; i < 16; i += 4) {
      ushort4 o;
      o.x = f2bf(t[eo + i + 0][dd]);
      o.y = f2bf(t[eo + i + 1][dd]);
      o.z = f2bf(t[eo + i + 2][dd]);
      o.w = f2bf(t[eo + i + 3][dd]);
      *(ushort4*)(dst + i) = o;
    }
    return;
  }
  blk -= 768;
  if (blk < 256) {                      // repack Wo
    const int k0 = (blk & 15) * 64;
    const int n0 = (blk >> 4) * 64;
    const int c = tid & 63, r4 = tid >> 6;
#pragma unroll
    for (int rr = 0; rr < 64; rr += 4)
      t[rr + r4][c] = Wo[(size_t)(k0 + rr + r4) * En + n0 + c];
    __syncthreads();
    const int n = tid >> 2, ko = (tid & 3) * 16;
    u16* dst = WoT + (size_t)(n0 + n) * (Hn * Dn) + k0 + ko;
#pragma unroll
    for (int i = 0; i < 16; i += 4) {
      ushort4 o;
      o.x = f2bf(t[ko + i + 0][n]);
      o.y = f2bf(t[ko + i + 1][n]);
      o.z = f2bf(t[ko + i + 2][n]);
      o.w = f2bf(t[ko + i + 3][n]);
      *(ushort4*)(dst + i) = o;
    }
    return;
  }
  blk -= 256;
  int n = blk * 256 + tid;              // bias pack
  if (n < 3 * Hn * Dn) {
    int sec = n >> 10, rr = n & 1023;
    const float* bs = (sec == 0) ? bq : (sec == 1) ? bk : bv;
    biasA[n] = bs[rr];
  }
}

// ---------------- out-proj GEMM (R0-proven 128^2, 4-wave) ----------------
template<int MODE>
__global__ __launch_bounds__(256) void gemm_bt(
    const u16* __restrict__ A, const u16* __restrict__ Bt,
    const float* __restrict__ bias, int M, int N, int K,
    u16* __restrict__ q_out, u16* __restrict__ k_out, u16* __restrict__ v_out,
    float* __restrict__ f_out)
{
  extern __shared__ __align__(16) u16 smem[];
  // layout: [buf0 A | buf1 A | buf0 B | buf1 B], each 4096 u16

  const int tid  = threadIdx.x;
  const int L    = blockIdx.x;
  const int m0   = (L & 63) * 128;
  const int n0   = (L >> 6) * 128;
  const int w    = tid >> 6;
  const int lane = tid & 63;
  const int quad = lane >> 4;
  const int l15  = lane & 15;
  const int mbase = (w >> 1) * 64;
  const int nbase = (w & 1) * 64;
  const int swz   = (quad ^ ((l15 >> 1) & 3)) * 8;   // swizzled 16B segment for frag reads

  f32x4 acc[4][4];
#pragma unroll
  for (int i = 0; i < 4; ++i)
#pragma unroll
    for (int j = 0; j < 4; ++j)
      acc[i][j] = (f32x4){0.f, 0.f, 0.f, 0.f};

  auto stage = [&](int k0, int bf) {
    u16* lA = smem + bf * 4096;
    u16* lB = smem + 2 * 4096 + bf * 4096;
#pragma unroll
    for (int c = 0; c < 2; ++c) {
      int idx = c * 256 + tid;        // 0..511
      int row = idx >> 2, sl = idx & 3;
      int sg = sl ^ ((row >> 1) & 3); // global 16B segment to fetch
      gload_lds16(A  + (size_t)(m0 + row) * K + k0 + sg * 8, &lA[idx * 8]);
      gload_lds16(Bt + (size_t)(n0 + row) * K + k0 + sg * 8, &lB[idx * 8]);
    }
  };

  stage(0, 0);
  int bf = 0;
  for (int k0 = 0; k0 < K; k0 += 32) {
    __syncthreads();                  // drains stage(k0); issued one compute ago
    if (k0 + 32 < K) stage(k0 + 32, bf ^ 1);
    const u16* lA = smem + bf * 4096;
    const u16* lB = smem + 2 * 4096 + bf * 4096;

    s16x8 af[4], bfr[4];
#pragma unroll
    for (int t = 0; t < 4; ++t) {
      af[t]  = *(const s16x8*)&lA[(mbase + t * 16 + l15) * 32 + swz];
      bfr[t] = *(const s16x8*)&lB[(nbase + t * 16 + l15) * 32 + swz];
    }
#pragma unroll
    for (int mt = 0; mt < 4; ++mt)
#pragma unroll
      for (int nt = 0; nt < 4; ++nt)
        acc[mt][nt] = MFMA16x16x32(af[mt], bfr[nt], acc[mt][nt], 0, 0, 0);
    bf ^= 1;
  }

  {
#pragma unroll
    for (int nt = 0; nt < 4; ++nt) {
      int col = n0 + nbase + nt * 16 + l15;
      float bv = bias[col];
#pragma unroll
      for (int mt = 0; mt < 4; ++mt)
#pragma unroll
        for (int r = 0; r < 4; ++r) {
          int row = m0 + mbase + mt * 16 + quad * 4 + r;
          f_out[(size_t)row * N + col] = acc[mt][nt][r] + bv;
        }
    }
  }
}

// ---------------- QKV GEMM: 256x128 block, wave-tile 128x64, BK=32 ----------
// The ONLY structural change vs the proven R0 kernel is the wave-tile:
// 128x64 per wave (acc 8x4) instead of 64x64. That cuts LDS-read bytes per
// MFMA-cycle from ~124% to ~93% (frag traffic = A 8KB + B 4KB per wave per
// K-tile vs 32 MFMA16) -- m201's geometry, which measured 62% MfmaUtil.
// Everything else is R0-proven: [row][32]-u16 LDS rows with seg ^= (row>>1)&3
// swizzle (0.08 conflicts/read measured), 16x16x32 fragments (rows=l15,
// chunk=quad), syncthreads-at-top prefetch loop, 3 blocks/CU.
// LDS = 2 x (256+128) x 32 x 2B = 48 KiB -> 3 blocks/CU; launch_bounds(256,3)
// caps VGPR at ~170 (acc 128 + bf 16 + streamed af + addr).
// Grid = 32 mi x 24 ni = 768 = 256 CU x 3 -> exactly one co-residency round.
// XCD map: ni-major (each XCD owns 3 consecutive ni -> its 3 B-panels =
// 768 KB stay L2-resident; A panels stream through L3).
__global__ __launch_bounds__(256, 3) void gemm_qkv2(
    const u16* __restrict__ A, const u16* __restrict__ Bt,
    const float* __restrict__ bias,
    u16* __restrict__ q_out, u16* __restrict__ k_out, u16* __restrict__ v_out)
{
  extern __shared__ __align__(16) u16 smem[];
  // layout: [A0 | A1 | B0 | B1] = [8192 | 8192 | 4096 | 4096] u16 (48 KiB)

  const int tid  = threadIdx.x;
  const int L    = blockIdx.x;
  const int xcd  = L & 7;
  const int rl   = L >> 3;                    // 0..95
  const int mi   = rl / 3;                    // 0..31
  const int ni   = xcd * 3 + (rl - mi * 3);   // 0..23
  const int m0   = mi * 256;
  const int n0   = ni * 128;

  const int w    = tid >> 6;
  const int lane = tid & 63;
  const int quad = lane >> 4;
  const int l15  = lane & 15;
  const int wm   = w >> 1;                    // 0..1 (m-half)
  const int wn   = w & 1;                     // 0..1 (n-half)
  const int swz  = (quad ^ ((l15 >> 1) & 3)) * 8;

  f32x4 acc[8][4];
#pragma unroll
  for (int i = 0; i < 8; ++i)
#pragma unroll
    for (int j = 0; j < 4; ++j)
      acc[i][j] = (f32x4){0.f, 0.f, 0.f, 0.f};

  auto stage = [&](int t) {
    const int db = t & 1;
    const int k0 = t * 32;
    u16* lA = smem + db * 8192;
    u16* lB = smem + 16384 + db * 4096;
#pragma unroll
    for (int c = 0; c < 4; ++c) {             // A: 256 rows
      int idx = c * 256 + tid;
      int row = idx >> 2, sl = idx & 3;
      int sg = sl ^ ((row >> 1) & 3);
      gload_lds16(A + (size_t)(m0 + row) * En + k0 + sg * 8, &lA[idx * 8]);
    }
#pragma unroll
    for (int c = 0; c < 2; ++c) {             // B: 128 rows
      int idx = c * 256 + tid;
      int row = idx >> 2, sl = idx & 3;
      int sg = sl ^ ((row >> 1) & 3);
      gload_lds16(Bt + (size_t)(n0 + row) * En + k0 + sg * 8, &lB[idx * 8]);
    }
  };

  stage(0);
  for (int t = 0; t < 32; ++t) {
    __syncthreads();                  // drains stage(t); issued one compute ago
    if (t + 1 < 32) stage(t + 1);
    const u16* cA = smem + (t & 1) * 8192;
    const u16* cB = smem + 16384 + (t & 1) * 4096;

    s16x8 bf4[4];
#pragma unroll
    for (int nt = 0; nt < 4; ++nt)
      bf4[nt] = *(const s16x8*)&cB[(wn * 64 + nt * 16 + l15) * 32 + swz];
#pragma unroll
    for (int mt = 0; mt < 8; ++mt) {
      s16x8 af = *(const s16x8*)&cA[(wm * 128 + mt * 16 + l15) * 32 + swz];
#pragma unroll
      for (int nt = 0; nt < 4; ++nt)
        acc[mt][nt] = MFMA16x16x32(af, bf4[nt], acc[mt][nt], 0, 0, 0);
    }
  }

  const int sec = n0 >> 10;                   // 0:Q 1:K 2:V (block-uniform)
  if (sec < 2) {
    const float osc = (sec == 0) ? QSC : 1.0f;
    u16* dst = (sec == 0) ? q_out : k_out;
#pragma unroll
    for (int nt = 0; nt < 4; ++nt) {
      int col = n0 + wn * 64 + nt * 16 + l15;
      float bv = bias[col];
      int rr = col & 1023;
      int h = rr >> 6, d = rr & 63;
#pragma unroll
      for (int mt = 0; mt < 8; ++mt)
#pragma unroll
        for (int r = 0; r < 4; ++r) {
          int row = m0 + wm * 128 + mt * 16 + quad * 4 + r;
          int b = row >> 11, s = row & 2047;
          dst[(((size_t)b * Hn + h) * Sn + s) * Dn + d] =
              f2bf((acc[mt][nt][r] + bv) * osc);
        }
    }
  } else {
    // V: 256x128 C-tile -> V^T, two 128-row passes through lC (aliases staging)
    __syncthreads();                          // all staging reads done
    u16* lC = smem;                           // 128 cols x 136 (34816 B < 48K)
    const int b = m0 >> 11;
#pragma unroll
    for (int p = 0; p < 2; ++p) {
      if (wm == p) {                          // wave-uniform
#pragma unroll
        for (int nt = 0; nt < 4; ++nt) {
          int cl = wn * 64 + nt * 16 + l15;
          float bv = bias[n0 + cl];
#pragma unroll
          for (int mt = 0; mt < 8; ++mt)
#pragma unroll
            for (int r = 0; r < 4; ++r)
              lC[cl * 136 + mt * 16 + quad * 4 + r] = f2bf(acc[mt][nt][r] + bv);
        }
      }
      __syncthreads();
      int c = tid >> 1, hh = tid & 1;
      int colg = (n0 & 1023) + c;
      int h = colg >> 6, d = colg & 63;
      int s0 = (m0 & 2047) + p * 128 + hh * 64;
      const uint4* src = (const uint4*)&lC[c * 136 + hh * 64];
      uint4* dstv = (uint4*)&v_out[(((size_t)b * Hn + h) * Dn + d) * Sn + s0];
#pragma unroll
      for (int i = 0; i < 8; ++i) dstv[i] = src[i];
      if (p == 0) __syncthreads();            // before pass 1 overwrites lC
    }
  }
}

// ---------------- flash attention v8 ----------------
__global__ __launch_bounds__(256, 4) void flash_attn(
    const u16* __restrict__ Qb, const u16* __restrict__ Kb,
    const u16* __restrict__ Vt, u16* __restrict__ conc)
{
  __shared__ __align__(16) u16 lK[2][64 * 64];   // [buf][kk][d] swizzled
  __shared__ __align__(16) u16 lV[2][64 * 64];   // [buf][d][kk] swizzled
  __shared__ __align__(16) u16 lP[4][16 * 64];   // [wave][q][kk], 16B XOR swizzle

  const int L   = blockIdx.x;
  const int bh  = L & 63;
  const int qt  = ((L >> 6) + (bh >> 2)) & 15;
  const int b   = bh >> 4, h = bh & 15;
  const int tid = threadIdx.x;
  const int w   = tid >> 6;
  const int lane = tid & 63;
  const int quad = lane >> 4;
  const int l15  = lane & 15;
  const int q0   = qt * 128;

  const u16* Qh = Qb + (size_t)bh * Sn * Dn;
  const u16* Kh = Kb + (size_t)bh * Sn * Dn;
  const u16* Vh = Vt + (size_t)bh * Dn * Sn;

  const int Q0m[2] = { q0 + w * 16, q0 + 64 + w * 16 };

  s16x8 aq[2][2];                      // Q fragments (B operand), pre-scaled
#pragma unroll
  for (int m = 0; m < 2; ++m)
#pragma unroll
    for (int c = 0; c < 2; ++c)
      aq[m][c] = *(const s16x8*)&Qh[(size_t)(Q0m[m] + l15) * Dn + c * 32 + quad * 8];

  s16x8 kones;                         // bf16 1.0 x8 (A-operand of l-sum MFMA)
#pragma unroll
  for (int i = 0; i < 8; ++i) kones[i] = (short)0x3F80;

  f32x4 acc[2][4];                     // O^T tiles: row d = dt*16+quad*4+r, col q = l15
#pragma unroll
  for (int m = 0; m < 2; ++m)
#pragma unroll
    for (int i = 0; i < 4; ++i) acc[m][i] = (f32x4){0.f, 0.f, 0.f, 0.f};
  const float NEG_INF = -__builtin_inff();
  float lrow[2] = {0.f, 0.f};

  const int sw0 = (quad ^ (l15 & 7)) * 8;
  const int sw1 = ((quad + 4) ^ (l15 & 7)) * 8;
  const int l7  = l15 & 7;

  const int ntiles = 2 * qt + 2;

  auto stage = [&](int kt) {
    int bufb = kt & 1;
    int kk0 = kt * 64;
#pragma unroll
    for (int c = 0; c < 2; ++c) {
      int idx = c * 256 + tid;         // 0..511
      int row = idx >> 3, sl = idx & 7;
      int sg = sl ^ (row & 7);
      gload_lds16(Kh + (size_t)(kk0 + row) * Dn + sg * 8, &lK[bufb][idx * 8]);
      gload_lds16(Vh + (size_t)row * Sn + kk0 + sg * 8, &lV[bufb][idx * 8]);
    }
  };

  stage(0);
  for (int kt = 0; kt < ntiles; ++kt) {
    const int kk0 = kt * 64;
    __syncthreads();                   // drains stage(kt); issued one compute ago
    if (kt + 1 < ntiles) stage(kt + 1);
    const u16* cK = lK[kt & 1];
    const u16* cV = lV[kt & 1];

#pragma unroll
    for (int m = 0; m < 2; ++m) {
      const int Q0 = Q0m[m];
      if (kk0 >= Q0 + 16) continue;    // sub-tile fully masked (wave-uniform)

      // S^T (pre-scaled, exp2 domain): lane = q-row l15, k = kk0 + ct*16 + quad*4 + r
      f32x4 sc[4];
#pragma unroll
      for (int ct = 0; ct < 4; ++ct) {
        s16x8 bk0 = *(const s16x8*)&cK[(ct * 16 + l15) * 64 + sw0];
        s16x8 bk1 = *(const s16x8*)&cK[(ct * 16 + l15) * 64 + sw1];
        f32x4 z = (f32x4){0.f, 0.f, 0.f, 0.f};
        z = MFMA16x16x32(bk0, aq[m][0], z, 0, 0, 0);
        z = MFMA16x16x32(bk1, aq[m][1], z, 0, 0, 0);
        sc[ct] = z;
      }

      const int qg = Q0 + l15;
      if (kk0 + 63 > Q0) {             // diagonal region: causal mask
#pragma unroll
        for (int ct = 0; ct < 4; ++ct)
#pragma unroll
          for (int r = 0; r < 4; ++r) {
            int kkg = kk0 + ct * 16 + quad * 4 + r;
            sc[ct][r] = (kkg <= qg) ? sc[ct][r] : NEG_INF;
          }
      }

      // P = exp2(sc) directly (shift-invariant softmax; masked -inf -> 0)
#pragma unroll
      for (int ct = 0; ct < 4; ++ct)
#pragma unroll
        for (int r = 0; r < 4; ++r)
          sc[ct][r] = __builtin_amdgcn_exp2f(sc[ct][r]);

      // P^T -> lP (truncation pack via v_perm; 16B XOR swizzle, bank-uniform)
      u16* Pw = &lP[w][0];
#pragma unroll
      for (int ct = 0; ct < 4; ++ct) {
        uint32_t d0 = __builtin_amdgcn_perm(f2u(sc[ct][1]), f2u(sc[ct][0]), 0x07060302);
        uint32_t d1 = __builtin_amdgcn_perm(f2u(sc[ct][3]), f2u(sc[ct][2]), 0x07060302);
        uint2 pk; pk.x = d0; pk.y = d1;
        int seg = (ct * 2 + (quad >> 1)) ^ l7;
        *(uint2*)&Pw[l15 * 64 + seg * 8 + (quad & 1) * 4] = pk;
      }
      __builtin_amdgcn_s_waitcnt(0xc07f);   // lgkmcnt(0)

      s16x8 ap0 = *(const s16x8*)&Pw[l15 * 64 + (quad ^ l7) * 8];
      s16x8 ap1 = *(const s16x8*)&Pw[l15 * 64 + ((quad + 4) ^ l7) * 8];

      // l-sum of (truncated) P via ones-row MFMA: C[i][q] = sum_k P[k][q]
      f32x4 zl = (f32x4){0.f, 0.f, 0.f, 0.f};
      zl = MFMA16x16x32(kones, ap0, zl, 0, 0, 0);
      zl = MFMA16x16x32(kones, ap1, zl, 0, 0, 0);

#pragma unroll
      for (int dt = 0; dt < 4; ++dt) {
        s16x8 bv0 = *(const s16x8*)&cV[(dt * 16 + l15) * 64 + sw0];
        s16x8 bv1 = *(const s16x8*)&cV[(dt * 16 + l15) * 64 + sw1];
        acc[m][dt] = MFMA16x16x32(bv0, ap0, acc[m][dt], 0, 0, 0);
        acc[m][dt] = MFMA16x16x32(bv1, ap1, acc[m][dt], 0, 0, 0);
      }
      lrow[m] += zl[0];
    }
  }

  // epilogue: O = acc^T / l -> conc [B, S, H*D] bf16 (lane l15 = q-row)
#pragma unroll
  for (int m = 0; m < 2; ++m) {
    float inv = 1.0f / lrow[m];
    int qg = Q0m[m] + l15;
#pragma unroll
    for (int dt = 0; dt < 4; ++dt) {
      ushort4 o;
      o.x = f2bf(acc[m][dt][0] * inv);
      o.y = f2bf(acc[m][dt][1] * inv);
      o.z = f2bf(acc[m][dt][2] * inv);
      o.w = f2bf(acc[m][dt][3] * inv);
      *(ushort4*)&conc[((size_t)b * Sn + qg) * (Hn * Dn) + h * Dn + dt * 16 + quad * 4] = o;
    }
  }
}

// ---------------- launch ----------------
extern "C" void kernel_launch(void* const* d_in, const int* in_sizes, int n_in,
                              void* d_out, int out_size, void* d_ws, size_t ws_size,
                              hipStream_t stream)
{
  const float* x  = (const float*)d_in[0];
  const float* Wq = (const float*)d_in[1];
  const float* Wk = (const float*)d_in[2];
  const float* Wv = (const float*)d_in[3];
  const float* bq = (const float*)d_in[4];
  const float* bk = (const float*)d_in[5];
  const float* bv = (const float*)d_in[6];
  const float* Wo = (const float*)d_in[7];
  const float* bo = (const float*)d_in[8];
  float* out = (float*)d_out;

  char* p = (char*)d_ws;
  u16* xb    = (u16*)p; p += (size_t)Bn * Sn * En * sizeof(u16);
  u16* WallT = (u16*)p; p += (size_t)3 * Hn * Dn * En * sizeof(u16);
  u16* WoT   = (u16*)p; p += (size_t)En * Hn * Dn * sizeof(u16);
  float* biasA = (float*)p; p += (size_t)3 * Hn * Dn * sizeof(float);
  u16* Qb    = (u16*)p; p += (size_t)Bn * Hn * Sn * Dn * sizeof(u16);
  u16* Kb    = (u16*)p; p += (size_t)Bn * Hn * Sn * Dn * sizeof(u16);
  u16* Vt    = (u16*)p; p += (size_t)Bn * Hn * Dn * Sn * sizeof(u16);
  u16* conc  = (u16*)p; p += (size_t)Bn * Sn * Hn * Dn * sizeof(u16);

  // fused prep: 8192 cast + 768 qkv-repack + 256 wo-repack + 12 bias
  prep_all<<<9228, 256, 0, stream>>>((const float4*)x, (ushort4*)xb,
                                     Wq, Wk, Wv, WallT, Wo, WoT,
                                     bq, bk, bv, biasA);

  // QKV: [8192,1024] x [1024,3072]; 256x128 blocks, wave-tile 128x64,
  // grid 768 = 256 CU x 3 blocks/CU, single co-residency round
  size_t smemq = 24576 * sizeof(u16);       // 48 KiB
  gemm_qkv2<<<768, 256, smemq, stream>>>(xb, WallT, biasA, Qb, Kb, Vt);

  flash_attn<<<(Sn / 128) * Bn * Hn, 256, 0, stream>>>(Qb, Kb, Vt, conc);

  // out: [8192,1024] x [1024,1024] + bo -> fp32 (R0-proven kernel)
  size_t smem1 = 4 * 4096 * sizeof(u16);    // 32 KB double-buffered staging
  gemm_bt<1><<<8 * 64, 256, smem1, stream>>>(
      conc, WoT, bo, Bn * Sn, En, Hn * Dn, nullptr, nullptr, nullptr, out);
}